// Round 2
// baseline (7359.239 us; speedup 1.0000x reference)
//
#include <hip/hip_runtime.h>

typedef _Float16 f16;
typedef _Float16 f16x4 __attribute__((ext_vector_type(4)));
typedef _Float16 f16x8 __attribute__((ext_vector_type(8)));
typedef float f32x4 __attribute__((ext_vector_type(4)));

#define TLEN 2048
#define NGP  640      // padded gate dim: 4 gates x 160
#define HROW 168      // padded LDS row length (bank-conflict break)
#define PF   4        // gates register-prefetch depth (statically unrolled)

__device__ __forceinline__ float sigm(float x) {
    return 1.0f / (1.0f + __expf(-x));
}
__device__ __forceinline__ float tanh_fast(float x) {
    // 1 - 2/(e^{2x}+1): handles +/-inf gracefully (no NaN), no clamps needed
    return 1.0f - 2.0f / (__expf(2.0f * x) + 1.0f);
}

// ---------------------------------------------------------------------------
// Prep: build MFMA B-fragment-ordered fp16 copies of w_ih / w_hh (padded
// 600->640 cols as 4 gates x 160, K padded to 160), and combined bias.
// Fragment layout: [nt(40)][kt(5)][lane(64)][e(8)], n = nt*16 + (lane&15),
// k = kt*32 + (lane>>4)*8 + e.  (Same mapping used for A and B packing, so
// any within-group k-permutation cancels.)
// ---------------------------------------------------------------------------
__global__ void prep_weights(const float* __restrict__ w_ih,
                             const float* __restrict__ w_hh,
                             const float* __restrict__ b_ih,
                             const float* __restrict__ b_hh,
                             f16* __restrict__ wihf, f16* __restrict__ whhf,
                             float* __restrict__ biasp)
{
    const int idx = blockIdx.x * blockDim.x + threadIdx.x;
    const int stride = gridDim.x * blockDim.x;
    for (int i = idx; i < 40 * 5 * 64 * 8; i += stride) {
        const int e = i & 7;
        const int lane = (i >> 3) & 63;
        const int kt = (i >> 9) % 5;
        const int nt = i / 2560;
        const int col = lane & 15, grp = lane >> 4;
        const int G = nt / 10, jt = nt % 10;
        const int j = jt * 16 + col;          // index within gate (0..159)
        const int k = kt * 32 + grp * 8 + e;  // K index (0..159)
        f16 vi = (f16)0.f, vh = (f16)0.f;
        if (j < 150) {
            const int row = G * 150 + j;      // row in original 600-row weight
            if (k < 144) vi = (f16)w_ih[row * 144 + k];
            if (k < 150) vh = (f16)w_hh[row * 150 + k];
        }
        wihf[i] = vi;
        whhf[i] = vh;
    }
    for (int i = idx; i < NGP; i += stride) {
        const int G = i / 160, j = i % 160;
        biasp[i] = (j < 150) ? (b_ih[G * 150 + j] + b_hh[G * 150 + j]) : 0.f;
    }
}

// ---------------------------------------------------------------------------
// Conv 3x3 VALID (17->4) + bias + ReLU, one block per (b,t).
// Writes y in [t*16+b][160] fp16 (K padded 144->160 with zeros).
// ---------------------------------------------------------------------------
__global__ __launch_bounds__(64) void conv_relu(
    const float* __restrict__ in, const float* __restrict__ cw,
    const float* __restrict__ cb, f16* __restrict__ y)
{
    __shared__ float s_in[1088];
    __shared__ float s_w[612];
    __shared__ float s_b[4];
    const int bt = blockIdx.x, tid = threadIdx.x;
    const float* ip = in + (size_t)bt * 1088;
    #pragma unroll
    for (int i = 0; i < 17; ++i) s_in[tid + i * 64] = ip[tid + i * 64];
    for (int i = tid; i < 612; i += 64) s_w[i] = cw[i];
    if (tid < 4) s_b[tid] = cb[tid];
    __syncthreads();
    const int b = bt >> 11, t = bt & 2047;
    f16* yr = y + (size_t)(t * 16 + b) * 160;
    for (int i = tid; i < 160; i += 64) {
        float v = 0.f;
        if (i < 144) {
            const int oc = i / 36, rr = i % 36, oy = rr / 6, ox = rr % 6;
            float acc = s_b[oc];
            const float* wp = s_w + oc * 153;
            const float* bp = s_in + oy * 8 + ox;
            #pragma unroll
            for (int ic = 0; ic < 17; ++ic)
                #pragma unroll
                for (int ky = 0; ky < 3; ++ky)
                    #pragma unroll
                    for (int kx = 0; kx < 3; ++kx)
                        acc += bp[ic * 64 + ky * 8 + kx] * wp[ic * 9 + ky * 3 + kx];
            v = fmaxf(acc, 0.f);
        }
        yr[i] = (f16)v;
    }
}

// ---------------------------------------------------------------------------
// gates_x = y @ w_ih^T + (b_ih + b_hh).  One block (10 waves) per timestep.
// Output layout [t][n(640)][b(16)] fp16 so the scan reads each lane's 4
// batch values as one f16x4 (and this store is one f16x4 per G per lane).
// ---------------------------------------------------------------------------
__global__ __launch_bounds__(640, 1) void gates_gemm(
    const f16* __restrict__ y, const f16* __restrict__ wihf,
    const float* __restrict__ biasp, f16* __restrict__ gates)
{
    const int tid = threadIdx.x, wv = tid >> 6, lane = tid & 63;
    const int col = lane & 15, grp = lane >> 4;
    const int t = blockIdx.x;
    f16x8 a[5];
    const f16* yr = y + (size_t)(t * 16 + col) * 160;
    #pragma unroll
    for (int kt = 0; kt < 5; ++kt)
        a[kt] = *(const f16x8*)(yr + kt * 32 + grp * 8);
    const int n0 = wv * 16 + col;
    #pragma unroll
    for (int G = 0; G < 4; ++G) {
        f32x4 acc = {0.f, 0.f, 0.f, 0.f};
        const f16* wf = wihf + (size_t)((G * 10 + wv) * 5) * 512;
        #pragma unroll
        for (int kt = 0; kt < 5; ++kt) {
            f16x8 bf = *(const f16x8*)(wf + kt * 512 + lane * 8);
            acc = __builtin_amdgcn_mfma_f32_16x16x32_f16(a[kt], bf, acc, 0, 0, 0);
        }
        const int n = G * 160 + n0;
        const float bb = biasp[n];
        f16x4 st;
        #pragma unroll
        for (int r = 0; r < 4; ++r) st[r] = (f16)(acc[r] + bb);
        *(f16x4*)(gates + ((size_t)t * NGP + n) * 16 + grp * 4) = st;
    }
}

// ---------------------------------------------------------------------------
// Persistent single-workgroup LSTM scan.  640 threads = 10 waves; wave wv
// owns j-slice [16wv,16wv+16) x all 4 gates (i/f/g/o lane-local in the MFMA
// C layout: col=lane&15 -> batch m, row=(lane>>4)*4+r -> ... m=batch here).
// w_hh B-fragments live in VGPRs; h double-buffered fp16 in LDS.
// gates_x is software-pipelined PF=4 steps ahead in registers; the per-step
// barrier is a RAW s_barrier with only lgkmcnt drained, so the global
// prefetch loads stay in flight across barriers (counted vmcnt).
// ---------------------------------------------------------------------------
__global__ __launch_bounds__(640, 1) void lstm_scan(
    const f16* __restrict__ gates, const f16* __restrict__ whhf,
    const float* __restrict__ last_w, const float* __restrict__ last_b,
    float* __restrict__ out)
{
    __shared__ f16 hbuf[2][16][HROW];
    const int tid = threadIdx.x, wv = tid >> 6, lane = tid & 63;
    const int col = lane & 15, grp = lane >> 4;
    const int n0 = wv * 16 + col;

    for (int i = tid; i < 2 * 16 * HROW; i += 640) ((f16*)hbuf)[i] = (f16)0.f;

    f16x8 bfrag[4][5];
    #pragma unroll
    for (int G = 0; G < 4; ++G)
        #pragma unroll
        for (int kt = 0; kt < 5; ++kt)
            bfrag[G][kt] =
                *(const f16x8*)(whhf + (size_t)(((G * 10 + wv) * 5 + kt) * 64 + lane) * 8);

    float cst[4] = {0.f, 0.f, 0.f, 0.f};
    __syncthreads();   // one-time full drain; pipeline starts after this

    // Per-lane gates base: element (t*640 + G*160 + n0)*16 + grp*4
    const f16* gbase = gates + (size_t)n0 * 16 + grp * 4;

    // Prologue: prefetch steps 0..PF-1 into registers (static indices only).
    f16x4 pf[PF][4];
    #pragma unroll
    for (int p = 0; p < PF; ++p)
        #pragma unroll
        for (int G = 0; G < 4; ++G)
            pf[p][G] = *(const f16x4*)(gbase + ((size_t)p * NGP + G * 160) * 16);

    for (int tb = 0; tb < TLEN; tb += PF) {
        #pragma unroll
        for (int p = 0; p < PF; ++p) {
            const int t = tb + p;
            const int cur = t & 1;

            // h fragment from LDS (written by all waves last step)
            f16x8 a[5];
            #pragma unroll
            for (int kt = 0; kt < 5; ++kt)
                a[kt] = *(const f16x8*)(&hbuf[cur][col][kt * 32 + grp * 8]);

            // Init accumulators from the prefetched gates_x (consumes pf[p])
            f32x4 acc[4];
            #pragma unroll
            for (int G = 0; G < 4; ++G) {
                acc[G][0] = (float)pf[p][G][0];
                acc[G][1] = (float)pf[p][G][1];
                acc[G][2] = (float)pf[p][G][2];
                acc[G][3] = (float)pf[p][G][3];
            }

            // Issue prefetch for step t+PF into the just-freed slot.
            {
                int tn = t + PF;
                if (tn >= TLEN) tn = t;   // tail: dummy reload, never consumed
                #pragma unroll
                for (int G = 0; G < 4; ++G)
                    pf[p][G] = *(const f16x4*)(gbase + ((size_t)tn * NGP + G * 160) * 16);
            }

            // h @ w_hh^T (+ gates_x via C-init)
            #pragma unroll
            for (int G = 0; G < 4; ++G)
                #pragma unroll
                for (int kt = 0; kt < 5; ++kt)
                    acc[G] = __builtin_amdgcn_mfma_f32_16x16x32_f16(
                        a[kt], bfrag[G][kt], acc[G], 0, 0, 0);

            // Lane-local activations + state update; write h to other buffer.
            #pragma unroll
            for (int r = 0; r < 4; ++r) {
                const float c = sigm(acc[1][r]) * cst[r]
                              + sigm(acc[0][r]) * tanh_fast(acc[2][r]);
                cst[r] = c;
                hbuf[cur ^ 1][grp * 4 + r][n0] = (f16)(sigm(acc[3][r]) * tanh_fast(c));
            }

            // Raw barrier: drain LDS ops only; global prefetches stay in flight.
            asm volatile("s_waitcnt lgkmcnt(0)" ::: "memory");
            __builtin_amdgcn_s_barrier();
            __builtin_amdgcn_sched_barrier(0);
        }
    }

    // Final projection: h_T @ last_w^T + last_b  (step 2047 wrote hbuf[0]).
    if (tid < 32) {
        const int b = tid >> 1, o = tid & 1;
        float s = last_b[o];
        for (int j = 0; j < 150; ++j)
            s += (float)hbuf[0][b][j] * last_w[o * 150 + j];
        out[b * 2 + o] = s;
    }
}

// ---------------------------------------------------------------------------
extern "C" void kernel_launch(void* const* d_in, const int* in_sizes, int n_in,
                              void* d_out, int out_size, void* d_ws, size_t ws_size,
                              hipStream_t stream) {
    const float* inp    = (const float*)d_in[0];
    const float* conv_w = (const float*)d_in[1];
    const float* conv_b = (const float*)d_in[2];
    const float* w_ih   = (const float*)d_in[3];
    const float* w_hh   = (const float*)d_in[4];
    const float* b_ih   = (const float*)d_in[5];
    const float* b_hh   = (const float*)d_in[6];
    const float* last_w = (const float*)d_in[7];
    const float* last_b = (const float*)d_in[8];
    float* out = (float*)d_out;

    char* ws = (char*)d_ws;
    f16*   y     = (f16*)(ws);                               // 32768*160*2  = 10,485,760
    f16*   gates = (f16*)(ws + 10485760);                    // 2048*640*16*2= 41,943,040
    f16*   wihf  = (f16*)(ws + 10485760 + 41943040);         // 204,800
    f16*   whhf  = (f16*)(ws + 10485760 + 41943040 + 204800);// 204,800
    float* biasp = (float*)(ws + 10485760 + 41943040 + 409600); // 2,560

    prep_weights<<<120, 256, 0, stream>>>(w_ih, w_hh, b_ih, b_hh, wihf, whhf, biasp);
    conv_relu<<<32768, 64, 0, stream>>>(inp, conv_w, conv_b, y);
    gates_gemm<<<2048, 640, 0, stream>>>(y, wihf, biasp, gates);
    lstm_scan<<<1, 640, 0, stream>>>(gates, whhf, last_w, last_b, out);
}

// Round 3
// 2843.857 us; speedup vs baseline: 2.5878x; 2.5878x over previous
//
#include <hip/hip_runtime.h>

typedef _Float16 f16;
typedef _Float16 f16x4 __attribute__((ext_vector_type(4)));
typedef _Float16 f16x8 __attribute__((ext_vector_type(8)));
typedef float f32x4 __attribute__((ext_vector_type(4)));

#define TLEN 2048
#define NGP  640      // padded gate dim: 4 gates x 160

__device__ __forceinline__ f16x8 as_f16x8(f32x4 v) {
    union { f32x4 f; f16x8 h; } u; u.f = v; return u.h;
}

// ---------------------------------------------------------------------------
// Prep: MFMA B-fragment-ordered fp16 w_ih / w_hh (cols padded 600->640 as
// 4 gates x 160, K padded to 160), plus combined bias.
// Fragment layout: [nt(40)][kt(5)][lane(64)][e(8)], n = nt*16 + (lane&15),
// k = kt*32 + (lane>>4)*8 + e.  Same mapping used for A packing, so any
// within-group k-permutation cancels.
// ---------------------------------------------------------------------------
__global__ void prep_weights(const float* __restrict__ w_ih,
                             const float* __restrict__ w_hh,
                             const float* __restrict__ b_ih,
                             const float* __restrict__ b_hh,
                             f16* __restrict__ wihf, f16* __restrict__ whhf,
                             float* __restrict__ biasp)
{
    const int idx = blockIdx.x * blockDim.x + threadIdx.x;
    const int stride = gridDim.x * blockDim.x;
    for (int i = idx; i < 40 * 5 * 64 * 8; i += stride) {
        const int e = i & 7;
        const int lane = (i >> 3) & 63;
        const int kt = (i >> 9) % 5;
        const int nt = i / 2560;
        const int col = lane & 15, grp = lane >> 4;
        const int G = nt / 10, jt = nt % 10;
        const int j = jt * 16 + col;
        const int k = kt * 32 + grp * 8 + e;
        f16 vi = (f16)0.f, vh = (f16)0.f;
        if (j < 150) {
            const int row = G * 150 + j;
            if (k < 144) vi = (f16)w_ih[row * 144 + k];
            if (k < 150) vh = (f16)w_hh[row * 150 + k];
        }
        wihf[i] = vi;
        whhf[i] = vh;
    }
    for (int i = idx; i < NGP; i += stride) {
        const int G = i / 160, j = i % 160;
        biasp[i] = (j < 150) ? (b_ih[G * 150 + j] + b_hh[G * 150 + j]) : 0.f;
    }
}

// ---------------------------------------------------------------------------
// Conv 3x3 VALID (17->4) + bias + ReLU, one block per (b,t).
// Writes y in [t*16+b][160] fp16 (K padded 144->160 with zeros).
// ---------------------------------------------------------------------------
__global__ __launch_bounds__(64) void conv_relu(
    const float* __restrict__ in, const float* __restrict__ cw,
    const float* __restrict__ cb, f16* __restrict__ y)
{
    __shared__ float s_in[1088];
    __shared__ float s_w[612];
    __shared__ float s_b[4];
    const int bt = blockIdx.x, tid = threadIdx.x;
    const float* ip = in + (size_t)bt * 1088;
    #pragma unroll
    for (int i = 0; i < 17; ++i) s_in[tid + i * 64] = ip[tid + i * 64];
    for (int i = tid; i < 612; i += 64) s_w[i] = cw[i];
    if (tid < 4) s_b[tid] = cb[tid];
    __syncthreads();
    const int b = bt >> 11, t = bt & 2047;
    f16* yr = y + (size_t)(t * 16 + b) * 160;
    for (int i = tid; i < 160; i += 64) {
        float v = 0.f;
        if (i < 144) {
            const int oc = i / 36, rr = i % 36, oy = rr / 6, ox = rr % 6;
            float acc = s_b[oc];
            const float* wp = s_w + oc * 153;
            const float* bp = s_in + oy * 8 + ox;
            #pragma unroll
            for (int ic = 0; ic < 17; ++ic)
                #pragma unroll
                for (int ky = 0; ky < 3; ++ky)
                    #pragma unroll
                    for (int kx = 0; kx < 3; ++kx)
                        acc += bp[ic * 64 + ky * 8 + kx] * wp[ic * 9 + ky * 3 + kx];
            v = fmaxf(acc, 0.f);
        }
        yr[i] = (f16)v;
    }
}

// ---------------------------------------------------------------------------
// gates_x = y @ w_ih^T + (b_ih + b_hh).  One block (10 waves) per timestep.
// Output layout [t][n(640)][b(16)] fp16: scan reads each lane's 4 batch
// values as one f16x4.
// ---------------------------------------------------------------------------
__global__ __launch_bounds__(640, 1) void gates_gemm(
    const f16* __restrict__ y, const f16* __restrict__ wihf,
    const float* __restrict__ biasp, f16* __restrict__ gates)
{
    const int tid = threadIdx.x, wv = tid >> 6, lane = tid & 63;
    const int col = lane & 15, grp = lane >> 4;
    const int t = blockIdx.x;
    f16x8 a[5];
    const f16* yr = y + (size_t)(t * 16 + col) * 160;
    #pragma unroll
    for (int kt = 0; kt < 5; ++kt)
        a[kt] = *(const f16x8*)(yr + kt * 32 + grp * 8);
    const int n0 = wv * 16 + col;
    #pragma unroll
    for (int G = 0; G < 4; ++G) {
        f32x4 acc = {0.f, 0.f, 0.f, 0.f};
        const f16* wf = wihf + (size_t)((G * 10 + wv) * 5) * 512;
        #pragma unroll
        for (int kt = 0; kt < 5; ++kt) {
            f16x8 bf = *(const f16x8*)(wf + kt * 512 + lane * 8);
            acc = __builtin_amdgcn_mfma_f32_16x16x32_f16(a[kt], bf, acc, 0, 0, 0);
        }
        const int n = G * 160 + n0;
        const float bb = biasp[n];
        f16x4 st;
        #pragma unroll
        for (int r = 0; r < 4; ++r) st[r] = (f16)(acc[r] + bb);
        *(f16x4*)(gates + ((size_t)t * NGP + n) * 16 + grp * 4) = st;
    }
}

// ---------------------------------------------------------------------------
// Persistent single-workgroup LSTM scan (640 threads = 10 waves).
// - w_hh B-fragments pinned in VGPRs via asm (remat-proof).
// - h stored in MFMA-A-fragment order hN[buf][kt(5)][lane(64)][e(8)]:
//   value h[b = lane&15][j = kt*32 + (lane>>4)*8 + e].  Per-step reads are
//   5 linear ds_read_b128 (conflict-free, identical for every wave).
// - gates_x software-pipelined 2 steps ahead in named regs pA/pB.
// - Raw s_barrier per step drains lgkmcnt only; global prefetches stay
//   in flight across barriers.
// ---------------------------------------------------------------------------
__device__ __forceinline__ void lstm_step(
    int t, f16x4 (&pf)[4], const f16* __restrict__ gbase,
    const f32x4 (&bfrag)[4][5], f16* hNs, float (&cst)[4],
    int lane, int grp, int wbase)
{
    const int cur = t & 1;

    // Accumulator init from prefetched gates_x (consumes pf).
    f32x4 acc[4];
    #pragma unroll
    for (int G = 0; G < 4; ++G) {
        acc[G][0] = (float)pf[G][0];
        acc[G][1] = (float)pf[G][1];
        acc[G][2] = (float)pf[G][2];
        acc[G][3] = (float)pf[G][3];
    }

    // Refill this slot for step t+2 (loads stay in flight ~2 steps).
    {
        const int tn = (t + 2 < TLEN) ? t + 2 : t;
        #pragma unroll
        for (int G = 0; G < 4; ++G)
            pf[G] = *(const f16x4*)(gbase + ((size_t)tn * NGP + G * 160) * 16);
    }

    // h @ w_hh^T; one A-fragment live at a time (kt-outer).
    const f16* hr = hNs + cur * 2560 + lane * 8;
    #pragma unroll
    for (int kt = 0; kt < 5; ++kt) {
        const f16x8 a = *(const f16x8*)(hr + kt * 512);
        #pragma unroll
        for (int G = 0; G < 4; ++G)
            acc[G] = __builtin_amdgcn_mfma_f32_16x16x32_f16(
                a, as_f16x8(bfrag[G][kt]), acc[G], 0, 0, 0);
    }

    // Lane-local activations: shared-denominator form, 5 exp + 2 rcp per
    // value; +/-15 clamps make every path finite (no inf/inf).
    const float K1 = 1.4426950408889634f, K2 = 2.8853900817779268f;
    f16* hw = hNs + (cur ^ 1) * 2560 + wbase;
    #pragma unroll
    for (int r = 0; r < 4; ++r) {
        const float gi = fmaxf(acc[0][r], -15.f);
        const float gf = fmaxf(acc[1][r], -15.f);
        const float gg = fminf(acc[2][r],  15.f);
        const float go = fmaxf(acc[3][r], -15.f);
        const float ei = __builtin_amdgcn_exp2f(-K1 * gi);
        const float ef = __builtin_amdgcn_exp2f(-K1 * gf);
        const float eg = __builtin_amdgcn_exp2f( K2 * gg);
        const float eo = __builtin_amdgcn_exp2f(-K1 * go);
        const float ip1 = 1.f + ei, fp1 = 1.f + ef;
        const float gp1 = eg + 1.f, gm1 = eg - 1.f, op1 = 1.f + eo;
        const float dig = ip1 * gp1;
        // c = cst/(1+ef) + (eg-1)/((1+ei)(eg+1))  over common denominator
        const float num = cst[r] * dig + gm1 * fp1;
        const float c = num * __builtin_amdgcn_rcpf(fp1 * dig);
        cst[r] = c;
        const float ec = __builtin_amdgcn_exp2f(fminf(K2 * c, 40.f));
        const float h = (ec - 1.f) * __builtin_amdgcn_rcpf(op1 * (ec + 1.f));
        hw[r * 8] = (f16)h;
    }

    // Drain LDS ops only; global prefetches remain outstanding.
    asm volatile("s_waitcnt lgkmcnt(0)" ::: "memory");
    __builtin_amdgcn_s_barrier();
    __builtin_amdgcn_sched_barrier(0);
}

__global__ __launch_bounds__(640, 1) void lstm_scan(
    const f16* __restrict__ gates, const f16* __restrict__ whhf,
    const float* __restrict__ last_w, const float* __restrict__ last_b,
    float* __restrict__ out)
{
    __shared__ __align__(16) f16 hN[2 * 5 * 512];   // [buf][kt][lane][e]
    const int tid = threadIdx.x, wv = tid >> 6, lane = tid & 63;
    const int col = lane & 15, grp = lane >> 4;
    const int j0 = wv * 16 + col;                   // this lane's j column
    // write base: value (b=4grp+r, j0) at kt*512 + L*8 + e,
    // L = ((j0&31)>>3)*16 + b, e = j0&7
    const int wbase = (j0 >> 5) * 512 + (((j0 & 31) >> 3) * 16 + 4 * grp) * 8 + (j0 & 7);

    for (int i = tid; i < 2 * 5 * 512; i += 640) hN[i] = (f16)0.f;

    // Load + PIN w_hh fragments (opaque to the compiler -> no remat).
    f32x4 bfrag[4][5];
    #pragma unroll
    for (int G = 0; G < 4; ++G)
        #pragma unroll
        for (int kt = 0; kt < 5; ++kt) {
            bfrag[G][kt] =
                *(const f32x4*)(whhf + (size_t)(((G * 10 + wv) * 5 + kt) * 64 + lane) * 8);
            asm volatile("" : "+v"(bfrag[G][kt]));
        }

    float cst[4] = {0.f, 0.f, 0.f, 0.f};
    __syncthreads();

    const f16* gbase = gates + (size_t)j0 * 16 + grp * 4;

    // Prologue: prefetch steps 0 and 1.
    f16x4 pA[4], pB[4];
    #pragma unroll
    for (int G = 0; G < 4; ++G) {
        pA[G] = *(const f16x4*)(gbase + ((size_t)0 * NGP + G * 160) * 16);
        pB[G] = *(const f16x4*)(gbase + ((size_t)1 * NGP + G * 160) * 16);
    }

    #pragma unroll 1
    for (int tb = 0; tb < TLEN; tb += 2) {
        lstm_step(tb,     pA, gbase, bfrag, hN, cst, lane, grp, wbase);
        lstm_step(tb + 1, pB, gbase, bfrag, hN, cst, lane, grp, wbase);
    }

    // Final projection (step 2047 wrote buf 0): out = h_T @ last_w^T + last_b
    if (tid < 32) {
        const int b = tid >> 1, o = tid & 1;
        float s = last_b[o];
        for (int j = 0; j < 150; ++j) {
            const int elem = (j >> 5) * 512 + (((j & 31) >> 3) * 16 + b) * 8 + (j & 7);
            s += (float)hN[elem] * last_w[o * 150 + j];
        }
        out[b * 2 + o] = s;
    }
}

// ---------------------------------------------------------------------------
extern "C" void kernel_launch(void* const* d_in, const int* in_sizes, int n_in,
                              void* d_out, int out_size, void* d_ws, size_t ws_size,
                              hipStream_t stream) {
    const float* inp    = (const float*)d_in[0];
    const float* conv_w = (const float*)d_in[1];
    const float* conv_b = (const float*)d_in[2];
    const float* w_ih   = (const float*)d_in[3];
    const float* w_hh   = (const float*)d_in[4];
    const float* b_ih   = (const float*)d_in[5];
    const float* b_hh   = (const float*)d_in[6];
    const float* last_w = (const float*)d_in[7];
    const float* last_b = (const float*)d_in[8];
    float* out = (float*)d_out;

    char* ws = (char*)d_ws;
    f16*   y     = (f16*)(ws);                                  // 10,485,760 B
    f16*   gates = (f16*)(ws + 10485760);                       // 41,943,040 B
    f16*   wihf  = (f16*)(ws + 10485760 + 41943040);            // 204,800 B
    f16*   whhf  = (f16*)(ws + 10485760 + 41943040 + 204800);   // 204,800 B
    float* biasp = (float*)(ws + 10485760 + 41943040 + 409600); // 2,560 B

    prep_weights<<<120, 256, 0, stream>>>(w_ih, w_hh, b_ih, b_hh, wihf, whhf, biasp);
    conv_relu<<<32768, 64, 0, stream>>>(inp, conv_w, conv_b, y);
    gates_gemm<<<2048, 640, 0, stream>>>(y, wihf, biasp, gates);
    lstm_scan<<<1, 640, 0, stream>>>(gates, whhf, last_w, last_b, out);
}

// Round 4
// 1552.790 us; speedup vs baseline: 4.7394x; 1.8315x over previous
//
#include <hip/hip_runtime.h>

typedef _Float16 f16;
typedef _Float16 f16x4 __attribute__((ext_vector_type(4)));
typedef _Float16 f16x8 __attribute__((ext_vector_type(8)));
typedef float f32x4 __attribute__((ext_vector_type(4)));

#define TLEN 2048
#define NGP  640      // padded gate dim: 4 gates x 160
#define K1   1.4426950408889634f   // log2(e)
#define K2   2.8853900817779268f   // 2*log2(e)

__device__ __forceinline__ f16x8 as_f16x8(f32x4 v) {
    union { f32x4 f; f16x8 h; } u; u.f = v; return u.h;
}

// ---------------------------------------------------------------------------
// Prep: MFMA B-fragment-ordered fp16 w_ih / w_hh, PRE-SCALED per gate so the
// scan's exp2 args need no multiply:  i,f,o rows * -K1 ; g rows * +K2.
// Fragment layout: [nt(40)][kt(5)][lane(64)][e(8)], n = nt*16 + (lane&15),
// k = kt*32 + (lane>>4)*8 + e.  Same mapping used for A packing, so any
// within-group k-permutation cancels.  biasp gets the same per-gate scale.
// ---------------------------------------------------------------------------
__global__ void prep_weights(const float* __restrict__ w_ih,
                             const float* __restrict__ w_hh,
                             const float* __restrict__ b_ih,
                             const float* __restrict__ b_hh,
                             f16* __restrict__ wihf, f16* __restrict__ whhf,
                             float* __restrict__ biasp)
{
    const int idx = blockIdx.x * blockDim.x + threadIdx.x;
    const int stride = gridDim.x * blockDim.x;
    for (int i = idx; i < 40 * 5 * 64 * 8; i += stride) {
        const int e = i & 7;
        const int lane = (i >> 3) & 63;
        const int kt = (i >> 9) % 5;
        const int nt = i / 2560;
        const int col = lane & 15, grp = lane >> 4;
        const int G = nt / 10, jt = nt % 10;
        const int j = jt * 16 + col;
        const int k = kt * 32 + grp * 8 + e;
        const float sc = (G == 2) ? K2 : -K1;
        f16 vi = (f16)0.f, vh = (f16)0.f;
        if (j < 150) {
            const int row = G * 150 + j;
            if (k < 144) vi = (f16)(w_ih[row * 144 + k] * sc);
            if (k < 150) vh = (f16)(w_hh[row * 150 + k] * sc);
        }
        wihf[i] = vi;
        whhf[i] = vh;
    }
    for (int i = idx; i < NGP; i += stride) {
        const int G = i / 160, j = i % 160;
        const float sc = (G == 2) ? K2 : -K1;
        biasp[i] = (j < 150) ? (b_ih[G * 150 + j] + b_hh[G * 150 + j]) * sc : 0.f;
    }
}

// ---------------------------------------------------------------------------
// Conv 3x3 VALID (17->4) + bias + ReLU, one block per (b,t).
// Writes y in [t*16+b][160] fp16 (K padded 144->160 with zeros).
// ---------------------------------------------------------------------------
__global__ __launch_bounds__(64) void conv_relu(
    const float* __restrict__ in, const float* __restrict__ cw,
    const float* __restrict__ cb, f16* __restrict__ y)
{
    __shared__ float s_in[1088];
    __shared__ float s_w[612];
    __shared__ float s_b[4];
    const int bt = blockIdx.x, tid = threadIdx.x;
    const float* ip = in + (size_t)bt * 1088;
    #pragma unroll
    for (int i = 0; i < 17; ++i) s_in[tid + i * 64] = ip[tid + i * 64];
    for (int i = tid; i < 612; i += 64) s_w[i] = cw[i];
    if (tid < 4) s_b[tid] = cb[tid];
    __syncthreads();
    const int b = bt >> 11, t = bt & 2047;
    f16* yr = y + (size_t)(t * 16 + b) * 160;
    for (int i = tid; i < 160; i += 64) {
        float v = 0.f;
        if (i < 144) {
            const int oc = i / 36, rr = i % 36, oy = rr / 6, ox = rr % 6;
            float acc = s_b[oc];
            const float* wp = s_w + oc * 153;
            const float* bp = s_in + oy * 8 + ox;
            #pragma unroll
            for (int ic = 0; ic < 17; ++ic)
                #pragma unroll
                for (int ky = 0; ky < 3; ++ky)
                    #pragma unroll
                    for (int kx = 0; kx < 3; ++kx)
                        acc += bp[ic * 64 + ky * 8 + kx] * wp[ic * 9 + ky * 3 + kx];
            v = fmaxf(acc, 0.f);
        }
        yr[i] = (f16)v;
    }
}

// ---------------------------------------------------------------------------
// gates_x = y @ w_ih_scaled^T + bias_scaled.  One block (10 waves) per t.
// Output layout [b][t][n0(160)][G(4)] fp16: the scan's WG b reads its lane's
// 4 gate values as ONE f16x4, contiguous per (b,t) row.
// ---------------------------------------------------------------------------
__global__ __launch_bounds__(640, 1) void gates_gemm(
    const f16* __restrict__ y, const f16* __restrict__ wihf,
    const float* __restrict__ biasp, f16* __restrict__ gates2)
{
    const int tid = threadIdx.x, wv = tid >> 6, lane = tid & 63;
    const int col = lane & 15, grp = lane >> 4;
    const int t = blockIdx.x;
    f16x8 a[5];
    const f16* yr = y + (size_t)(t * 16 + col) * 160;
    #pragma unroll
    for (int kt = 0; kt < 5; ++kt)
        a[kt] = *(const f16x8*)(yr + kt * 32 + grp * 8);
    const int n0 = wv * 16 + col;
    f32x4 acc[4];
    float bb[4];
    #pragma unroll
    for (int G = 0; G < 4; ++G) {
        f32x4 v = {0.f, 0.f, 0.f, 0.f};
        const f16* wf = wihf + (size_t)((G * 10 + wv) * 5) * 512;
        #pragma unroll
        for (int kt = 0; kt < 5; ++kt) {
            f16x8 bf = *(const f16x8*)(wf + kt * 512 + lane * 8);
            v = __builtin_amdgcn_mfma_f32_16x16x32_f16(a[kt], bf, v, 0, 0, 0);
        }
        acc[G] = v;
        bb[G] = biasp[G * 160 + n0];
    }
    #pragma unroll
    for (int r = 0; r < 4; ++r) {
        f16x4 st;
        #pragma unroll
        for (int G = 0; G < 4; ++G) st[G] = (f16)(acc[G][r] + bb[G]);
        const int b = grp * 4 + r;
        *(f16x4*)(gates2 + ((size_t)(b * TLEN + t) * 160 + n0) * 4) = st;
    }
}

// ---------------------------------------------------------------------------
// Batch-parallel persistent LSTM scan: 16 WGs, ONE batch row each (the LSTM
// recurrence is independent per batch row).  640 threads = 10 waves; wave wv
// owns j-slice [16wv,16wv+16) x all 4 gates.  Only A-row 0 is real h (rows
// 1-15 stay zero -> their C rows are junk-but-finite and never read).
// Activations run on acc[*][0] only: 1/4 the per-lane VALU work of the
// single-WG version.  w_hh fragments pinned in VGPRs; h in LDS A-fragment
// order, double-buffered; gates prefetched 2 steps ahead (1 f16x4/lane).
// ---------------------------------------------------------------------------
__device__ __forceinline__ void lstm_step(
    int t, f16x4& pf, const f16* __restrict__ gb,
    const f32x4 (&bfrag)[4][5], f16* hNs, float& cst,
    int lane, bool act, int wel)
{
    const int cur = t & 1;

    // Gate-x init (pre-scaled; same value loaded by all grp's of a col).
    f32x4 acc[4];
    #pragma unroll
    for (int G = 0; G < 4; ++G)
        acc[G] = (f32x4){(float)pf[G], 0.f, 0.f, 0.f};

    // Refill prefetch slot for step t+2 (stays in flight across barriers).
    {
        const int tn = (t + 2 < TLEN) ? t + 2 : TLEN - 1;
        pf = *(const f16x4*)(gb + (size_t)tn * NGP);
    }

    // h @ w_hh^T (scaled): 5 linear ds_read_b128 + 20 MFMA.
    const f16* hr = hNs + cur * 2560 + lane * 8;
    #pragma unroll
    for (int kt = 0; kt < 5; ++kt) {
        const f16x8 a = *(const f16x8*)(hr + kt * 512);
        #pragma unroll
        for (int G = 0; G < 4; ++G)
            acc[G] = __builtin_amdgcn_mfma_f32_16x16x32_f16(
                a, as_f16x8(bfrag[G][kt]), acc[G], 0, 0, 0);
    }

    // Activations for row 0 only.  Args are pre-scaled: ai = -K1*i_raw etc,
    // so exp2 applies directly.  One-sided clamps keep all paths finite.
    const float ai = fminf(acc[0][0], 38.f);
    const float af = fminf(acc[1][0], 38.f);
    const float ag = fminf(acc[2][0], 38.f);
    const float ao = fminf(acc[3][0], 38.f);
    const float ei = __builtin_amdgcn_exp2f(ai);   // e^{-i}
    const float ef = __builtin_amdgcn_exp2f(af);   // e^{-f}
    const float eg = __builtin_amdgcn_exp2f(ag);   // e^{2g}
    const float eo = __builtin_amdgcn_exp2f(ao);   // e^{-o}
    const float ip1 = 1.f + ei, fp1 = 1.f + ef;
    const float gp1 = eg + 1.f, gm1 = eg - 1.f, op1 = 1.f + eo;
    const float dig = ip1 * gp1;
    const float num = cst * dig + gm1 * fp1;
    const float c = num * __builtin_amdgcn_rcpf(fp1 * dig);
    cst = c;
    const float ec = __builtin_amdgcn_exp2f(fminf(K2 * c, 80.f));
    const float h = (ec - 1.f) * __builtin_amdgcn_rcpf(op1 * (ec + 1.f));
    if (act) hNs[(cur ^ 1) * 2560 + wel] = (f16)h;

    // Drain LDS ops only; global prefetches remain outstanding.
    asm volatile("s_waitcnt lgkmcnt(0)" ::: "memory");
    __builtin_amdgcn_s_barrier();
    __builtin_amdgcn_sched_barrier(0);
}

__global__ __launch_bounds__(640, 1) void lstm_scan(
    const f16* __restrict__ gates2, const f16* __restrict__ whhf,
    const float* __restrict__ last_w, const float* __restrict__ last_b,
    float* __restrict__ out)
{
    __shared__ __align__(16) f16 hN[2 * 2560];   // [buf][kt(5)][lane(64)][e(8)]
    const int b = blockIdx.x;
    const int tid = threadIdx.x, wv = tid >> 6, lane = tid & 63;
    const int col = lane & 15, grp = lane >> 4;
    const int j0 = wv * 16 + col;
    const bool act = (grp == 0);
    // write element for (row0, j0)
    const int wel = (j0 >> 5) * 512 + ((j0 & 31) >> 3) * 128 + (j0 & 7);

    for (int i = tid; i < 2 * 2560; i += 640) hN[i] = (f16)0.f;

    // Load + PIN w_hh fragments (opaque to the compiler -> no remat).
    f32x4 bfrag[4][5];
    #pragma unroll
    for (int G = 0; G < 4; ++G)
        #pragma unroll
        for (int kt = 0; kt < 5; ++kt) {
            bfrag[G][kt] =
                *(const f32x4*)(whhf + (size_t)(((G * 10 + wv) * 5 + kt) * 64 + lane) * 8);
            asm volatile("" : "+v"(bfrag[G][kt]));
        }

    float cst = 0.f;
    __syncthreads();

    // Per-lane gates base for this WG's batch row.
    const f16* gb = gates2 + ((size_t)b * TLEN * 160 + j0) * 4;

    f16x4 pA = *(const f16x4*)(gb);
    f16x4 pB = *(const f16x4*)(gb + NGP);

    #pragma unroll 1
    for (int tb = 0; tb < TLEN; tb += 2) {
        lstm_step(tb,     pA, gb, bfrag, hN, cst, lane, act, wel);
        lstm_step(tb + 1, pB, gb, bfrag, hN, cst, lane, act, wel);
    }

    // Final projection (step 2047 wrote buf 0): out[b] = h_T @ last_w^T + last_b
    if (tid < 2) {
        float s = last_b[tid];
        for (int j = 0; j < 150; ++j) {
            const int elem = (j >> 5) * 512 + ((j & 31) >> 3) * 128 + (j & 7);
            s += (float)hN[elem] * last_w[tid * 150 + j];
        }
        out[b * 2 + tid] = s;
    }
}

// ---------------------------------------------------------------------------
extern "C" void kernel_launch(void* const* d_in, const int* in_sizes, int n_in,
                              void* d_out, int out_size, void* d_ws, size_t ws_size,
                              hipStream_t stream) {
    const float* inp    = (const float*)d_in[0];
    const float* conv_w = (const float*)d_in[1];
    const float* conv_b = (const float*)d_in[2];
    const float* w_ih   = (const float*)d_in[3];
    const float* w_hh   = (const float*)d_in[4];
    const float* b_ih   = (const float*)d_in[5];
    const float* b_hh   = (const float*)d_in[6];
    const float* last_w = (const float*)d_in[7];
    const float* last_b = (const float*)d_in[8];
    float* out = (float*)d_out;

    char* ws = (char*)d_ws;
    f16*   y      = (f16*)(ws);                                  // 10,485,760 B
    f16*   gates2 = (f16*)(ws + 10485760);                       // 41,943,040 B
    f16*   wihf   = (f16*)(ws + 10485760 + 41943040);            // 204,800 B
    f16*   whhf   = (f16*)(ws + 10485760 + 41943040 + 204800);   // 204,800 B
    float* biasp  = (float*)(ws + 10485760 + 41943040 + 409600); // 2,560 B

    prep_weights<<<120, 256, 0, stream>>>(w_ih, w_hh, b_ih, b_hh, wihf, whhf, biasp);
    conv_relu<<<32768, 64, 0, stream>>>(inp, conv_w, conv_b, y);
    gates_gemm<<<2048, 640, 0, stream>>>(y, wihf, biasp, gates2);
    lstm_scan<<<16, 640, 0, stream>>>(gates2, whhf, last_w, last_b, out);
}

// Round 5
// 1519.348 us; speedup vs baseline: 4.8437x; 1.0220x over previous
//
#include <hip/hip_runtime.h>

typedef _Float16 f16;
typedef _Float16 f16x4 __attribute__((ext_vector_type(4)));
typedef _Float16 f16x8 __attribute__((ext_vector_type(8)));
typedef float f32x4 __attribute__((ext_vector_type(4)));

#define TLEN 2048
#define TPAD 2050     // gates2 time extent (2 pad steps so prefetch needs no clamp)
#define NGP  640      // padded gate dim: 4 gates x 160
#define K1   1.4426950408889634f   // log2(e)
#define K2   2.8853900817779268f   // 2*log2(e)

__device__ __forceinline__ f16x8 as_f16x8(f32x4 v) {
    union { f32x4 f; f16x8 h; } u; u.f = v; return u.h;
}

// ---------------------------------------------------------------------------
// Prep: MFMA B-fragment-ordered fp16 w_ih / w_hh, PRE-SCALED per gate so the
// scan's exp2 args need no multiply:  i,f,o rows * -K1 ; g rows * +K2.
// Fragment layout: [nt(40)][kt(5)][lane(64)][e(8)], n = nt*16 + (lane&15),
// k = kt*32 + (lane>>4)*8 + e.  Same mapping used for A packing, so any
// within-group k-permutation cancels.  biasp gets the same per-gate scale.
// ---------------------------------------------------------------------------
__global__ void prep_weights(const float* __restrict__ w_ih,
                             const float* __restrict__ w_hh,
                             const float* __restrict__ b_ih,
                             const float* __restrict__ b_hh,
                             f16* __restrict__ wihf, f16* __restrict__ whhf,
                             float* __restrict__ biasp)
{
    const int idx = blockIdx.x * blockDim.x + threadIdx.x;
    const int stride = gridDim.x * blockDim.x;
    for (int i = idx; i < 40 * 5 * 64 * 8; i += stride) {
        const int e = i & 7;
        const int lane = (i >> 3) & 63;
        const int kt = (i >> 9) % 5;
        const int nt = i / 2560;
        const int col = lane & 15, grp = lane >> 4;
        const int G = nt / 10, jt = nt % 10;
        const int j = jt * 16 + col;
        const int k = kt * 32 + grp * 8 + e;
        const float sc = (G == 2) ? K2 : -K1;
        f16 vi = (f16)0.f, vh = (f16)0.f;
        if (j < 150) {
            const int row = G * 150 + j;
            if (k < 144) vi = (f16)(w_ih[row * 144 + k] * sc);
            if (k < 150) vh = (f16)(w_hh[row * 150 + k] * sc);
        }
        wihf[i] = vi;
        whhf[i] = vh;
    }
    for (int i = idx; i < NGP; i += stride) {
        const int G = i / 160, j = i % 160;
        const float sc = (G == 2) ? K2 : -K1;
        biasp[i] = (j < 150) ? (b_ih[G * 150 + j] + b_hh[G * 150 + j]) * sc : 0.f;
    }
}

// ---------------------------------------------------------------------------
// Conv 3x3 VALID (17->4) + bias + ReLU.  4 (b,t) tiles per 256-thread block
// (shared conv weights loaded once per block, 4x fewer blocks).
// Writes y in [t*16+b][160] fp16 (K padded 144->160 with zeros).
// ---------------------------------------------------------------------------
__global__ __launch_bounds__(256) void conv_relu(
    const float* __restrict__ in, const float* __restrict__ cw,
    const float* __restrict__ cb, f16* __restrict__ y)
{
    __shared__ float s_in[4][1088];
    __shared__ float s_w[612];
    __shared__ float s_b[4];
    const int tid = threadIdx.x, sub = tid >> 6, lt = tid & 63;
    const int bt = blockIdx.x * 4 + sub;
    const float* ip = in + (size_t)bt * 1088;
    #pragma unroll
    for (int i = 0; i < 17; ++i) s_in[sub][lt + i * 64] = ip[lt + i * 64];
    for (int i = tid; i < 612; i += 256) s_w[i] = cw[i];
    if (tid < 4) s_b[tid] = cb[tid];
    __syncthreads();
    const int b = bt >> 11, t = bt & 2047;
    f16* yr = y + (size_t)(t * 16 + b) * 160;
    for (int i = lt; i < 160; i += 64) {
        float v = 0.f;
        if (i < 144) {
            const int oc = i / 36, rr = i % 36, oy = rr / 6, ox = rr % 6;
            float acc = s_b[oc];
            const float* wp = s_w + oc * 153;
            const float* bp = &s_in[sub][oy * 8 + ox];
            #pragma unroll
            for (int ic = 0; ic < 17; ++ic)
                #pragma unroll
                for (int ky = 0; ky < 3; ++ky)
                    #pragma unroll
                    for (int kx = 0; kx < 3; ++kx)
                        acc += bp[ic * 64 + ky * 8 + kx] * wp[ic * 9 + ky * 3 + kx];
            v = fmaxf(acc, 0.f);
        }
        yr[i] = (f16)v;
    }
}

// ---------------------------------------------------------------------------
// gates_x = y @ w_ih_scaled^T + bias_scaled.  One block (10 waves) per t.
// Output layout [b][t(TPAD)][n0(160)][G(4)] fp16: scan WG b reads its lane's
// 4 gate values as ONE f16x4.  (2 pad timesteps are never written/consumed.)
// ---------------------------------------------------------------------------
__global__ __launch_bounds__(640, 1) void gates_gemm(
    const f16* __restrict__ y, const f16* __restrict__ wihf,
    const float* __restrict__ biasp, f16* __restrict__ gates2)
{
    const int tid = threadIdx.x, wv = tid >> 6, lane = tid & 63;
    const int col = lane & 15, grp = lane >> 4;
    const int t = blockIdx.x;
    f16x8 a[5];
    const f16* yr = y + (size_t)(t * 16 + col) * 160;
    #pragma unroll
    for (int kt = 0; kt < 5; ++kt)
        a[kt] = *(const f16x8*)(yr + kt * 32 + grp * 8);
    const int n0 = wv * 16 + col;
    f32x4 acc[4];
    float bb[4];
    #pragma unroll
    for (int G = 0; G < 4; ++G) {
        f32x4 v = {0.f, 0.f, 0.f, 0.f};
        const f16* wf = wihf + (size_t)((G * 10 + wv) * 5) * 512;
        #pragma unroll
        for (int kt = 0; kt < 5; ++kt) {
            f16x8 bf = *(const f16x8*)(wf + kt * 512 + lane * 8);
            v = __builtin_amdgcn_mfma_f32_16x16x32_f16(a[kt], bf, v, 0, 0, 0);
        }
        acc[G] = v;
        bb[G] = biasp[G * 160 + n0];
    }
    #pragma unroll
    for (int r = 0; r < 4; ++r) {
        f16x4 st;
        #pragma unroll
        for (int G = 0; G < 4; ++G) st[G] = (f16)(acc[G][r] + bb[G]);
        const int b = grp * 4 + r;
        *(f16x4*)(gates2 + ((size_t)(b * TPAD + t) * 160 + n0) * 4) = st;
    }
}

// ---------------------------------------------------------------------------
// Batch-parallel persistent LSTM scan: 16 WGs, one batch row each.
// w_hh fragments loaded VOLATILE -> compiler cannot rematerialize them from
// memory inside the loop; they stay resident in VGPRs (the round-4 version
// reloaded all 20 fragments from L2 every step: VGPR_Count was 68 < the 80
// the fragments need).  h in LDS A-fragment order, double-buffered; gates
// prefetched 2 steps ahead; raw s_barrier drains lgkmcnt only.
// ---------------------------------------------------------------------------
__device__ __forceinline__ void lstm_step(
    int t, f16x4& pf, const f16* __restrict__ gb,
    const f32x4 (&bfrag)[4][5], f16* hNs, float& cst,
    int lane, bool act, int wel)
{
    const int cur = t & 1;

    // Gate-x init (pre-scaled).
    f32x4 acc[4];
    #pragma unroll
    for (int G = 0; G < 4; ++G)
        acc[G] = (f32x4){(float)pf[G], 0.f, 0.f, 0.f};

    // Refill prefetch slot for step t+2 (no clamp: gates2 is TPAD-padded;
    // slots loaded for t>=TLEN are never consumed).
    pf = *(const f16x4*)(gb + (size_t)(t + 2) * NGP);

    // h @ w_hh^T (scaled): 5 linear ds_read_b128 + 20 MFMA.
    const f16* hr = hNs + cur * 2560 + lane * 8;
    #pragma unroll
    for (int kt = 0; kt < 5; ++kt) {
        const f16x8 a = *(const f16x8*)(hr + kt * 512);
        #pragma unroll
        for (int G = 0; G < 4; ++G)
            acc[G] = __builtin_amdgcn_mfma_f32_16x16x32_f16(
                a, as_f16x8(bfrag[G][kt]), acc[G], 0, 0, 0);
    }

    // Activations for row 0 only (pre-scaled args; exp2 applies directly).
    const float ai = fminf(acc[0][0], 38.f);
    const float af = fminf(acc[1][0], 38.f);
    const float ag = fminf(acc[2][0], 38.f);
    const float ao = fminf(acc[3][0], 38.f);
    const float ei = __builtin_amdgcn_exp2f(ai);   // e^{-i}
    const float ef = __builtin_amdgcn_exp2f(af);   // e^{-f}
    const float eg = __builtin_amdgcn_exp2f(ag);   // e^{2g}
    const float eo = __builtin_amdgcn_exp2f(ao);   // e^{-o}
    const float ip1 = 1.f + ei, fp1 = 1.f + ef;
    const float gp1 = eg + 1.f, gm1 = eg - 1.f, op1 = 1.f + eo;
    const float dig = ip1 * gp1;
    const float num = cst * dig + gm1 * fp1;
    const float c = num * __builtin_amdgcn_rcpf(fp1 * dig);
    cst = c;
    const float ec = __builtin_amdgcn_exp2f(fminf(K2 * c, 80.f));
    const float h = (ec - 1.f) * __builtin_amdgcn_rcpf(op1 * (ec + 1.f));
    if (act) hNs[(cur ^ 1) * 2560 + wel] = (f16)h;

    // Drain LDS ops only; global prefetches remain outstanding.
    asm volatile("s_waitcnt lgkmcnt(0)" ::: "memory");
    __builtin_amdgcn_s_barrier();
    __builtin_amdgcn_sched_barrier(0);
}

__global__ __launch_bounds__(640, 1) void lstm_scan(
    const f16* __restrict__ gates2, const f16* __restrict__ whhf,
    const float* __restrict__ last_w, const float* __restrict__ last_b,
    float* __restrict__ out)
{
    __shared__ __align__(16) f16 hN[2 * 2560];   // [buf][kt(5)][lane(64)][e(8)]
    const int b = blockIdx.x;
    const int tid = threadIdx.x, wv = tid >> 6, lane = tid & 63;
    const int col = lane & 15, grp = lane >> 4;
    const int j0 = wv * 16 + col;
    const bool act = (grp == 0);
    const int wel = (j0 >> 5) * 512 + ((j0 & 31) >> 3) * 128 + (j0 & 7);

    for (int i = tid; i < 2 * 2560; i += 640) hN[i] = (f16)0.f;

    // VOLATILE fragment loads: cannot be re-executed -> values must stay
    // live in VGPRs for the whole kernel (~80 VGPRs, budget ~168 at 10 waves).
    f32x4 bfrag[4][5];
    #pragma unroll
    for (int G = 0; G < 4; ++G)
        #pragma unroll
        for (int kt = 0; kt < 5; ++kt) {
            const volatile float* vp = (const volatile float*)
                (whhf + (size_t)(((G * 10 + wv) * 5 + kt) * 64 + lane) * 8);
            f32x4 v;
            v[0] = vp[0]; v[1] = vp[1]; v[2] = vp[2]; v[3] = vp[3];
            bfrag[G][kt] = v;
        }

    float cst = 0.f;
    __syncthreads();

    const f16* gb = gates2 + ((size_t)b * TPAD * 160 + j0) * 4;

    f16x4 pA = *(const f16x4*)(gb);
    f16x4 pB = *(const f16x4*)(gb + NGP);

    #pragma unroll 1
    for (int tb = 0; tb < TLEN; tb += 2) {
        lstm_step(tb,     pA, gb, bfrag, hN, cst, lane, act, wel);
        lstm_step(tb + 1, pB, gb, bfrag, hN, cst, lane, act, wel);
    }

    // Final projection (step 2047 wrote buf 0): out[b] = h_T @ last_w^T + last_b
    if (tid < 2) {
        float s = last_b[tid];
        for (int j = 0; j < 150; ++j) {
            const int elem = (j >> 5) * 512 + ((j & 31) >> 3) * 128 + (j & 7);
            s += (float)hN[elem] * last_w[tid * 150 + j];
        }
        out[b * 2 + tid] = s;
    }
}

// ---------------------------------------------------------------------------
extern "C" void kernel_launch(void* const* d_in, const int* in_sizes, int n_in,
                              void* d_out, int out_size, void* d_ws, size_t ws_size,
                              hipStream_t stream) {
    const float* inp    = (const float*)d_in[0];
    const float* conv_w = (const float*)d_in[1];
    const float* conv_b = (const float*)d_in[2];
    const float* w_ih   = (const float*)d_in[3];
    const float* w_hh   = (const float*)d_in[4];
    const float* b_ih   = (const float*)d_in[5];
    const float* b_hh   = (const float*)d_in[6];
    const float* last_w = (const float*)d_in[7];
    const float* last_b = (const float*)d_in[8];
    float* out = (float*)d_out;

    char* ws = (char*)d_ws;
    f16*   y      = (f16*)(ws);                        // 32768*160*2      = 10,485,760 B
    f16*   gates2 = (f16*)(ws + 10485760);             // 16*2050*640*2    = 41,984,000 B
    f16*   wihf   = (f16*)(ws + 10485760 + 41984000);          // 204,800 B
    f16*   whhf   = (f16*)(ws + 10485760 + 41984000 + 204800); // 204,800 B
    float* biasp  = (float*)(ws + 10485760 + 41984000 + 409600); // 2,560 B

    prep_weights<<<120, 256, 0, stream>>>(w_ih, w_hh, b_ih, b_hh, wihf, whhf, biasp);
    conv_relu<<<8192, 256, 0, stream>>>(inp, conv_w, conv_b, y);
    gates_gemm<<<2048, 640, 0, stream>>>(y, wihf, biasp, gates2);
    lstm_scan<<<16, 640, 0, stream>>>(gates2, whhf, last_w, last_b, out);
}